// Round 8
// baseline (253.704 us; speedup 1.0000x reference)
//
#include <hip/hip_runtime.h>
#include <cmath>
#include <cstdint>

// B=64, T=64, W=20, D=1024, K=4, STRIDE=4 ; conv lengths 64->16->4->1 ; T_total=21

typedef __bf16 bf16_t;
typedef bf16_t bf16x8 __attribute__((ext_vector_type(8)));
typedef bf16_t bf16x4 __attribute__((ext_vector_type(4)));
typedef float  f32x4  __attribute__((ext_vector_type(4)));

__device__ __forceinline__ void gload_lds16(const void* g, void* l) {
    __builtin_amdgcn_global_load_lds(
        (const __attribute__((address_space(1))) void*)g,
        (__attribute__((address_space(3))) void*)l, 16, 0, 0);
}

// swizzled LDS offset (bf16 units): physical chunk = c ^ (row&7). [R3: conflicts->0]
__device__ __forceinline__ int swz(int r, int c) { return (r * 8 + (c ^ (r & 7))) * 8; }

// conv1d stack row remap -> VC row j*21 + t
__device__ __forceinline__ int remap1(int gm) {
    if (gm < 1024) return (gm >> 4) * 21 + (gm & 15);
    if (gm < 1280) { int g = gm - 1024; return (g >> 2) * 21 + 16 + (g & 3); }
    return (gm - 1280) * 21 + 20;
}

// ---------------- prep: 3 weight transposes + 4 casts in ONE kernel -----------
__global__ void prep_kernel(
    const float* __restrict__ c0w, const float* __restrict__ c1w,
    const float* __restrict__ c2w,
    bf16_t* __restrict__ WT0, bf16_t* __restrict__ WT1, bf16_t* __restrict__ WT2,
    const float* __restrict__ video, bf16_t* __restrict__ Vb,
    const float* __restrict__ words, bf16_t* __restrict__ Wordsb,
    const float* __restrict__ c1dw, bf16_t* __restrict__ C1b,
    const float* __restrict__ fcw, bf16_t* __restrict__ Fb)
{
    int bx = blockIdx.x;
    if (bx < 12288) {                       // transpose: wt[o][k*1024+i] = w[o][i*4+k]
        const float* w; bf16_t* wt;
        if (bx < 4096)      { w = c0w; wt = WT0; }
        else if (bx < 8192) { w = c1w; wt = WT1; bx -= 4096; }
        else                { w = c2w; wt = WT2; bx -= 8192; }
        int idx = bx * 256 + threadIdx.x;   // (o,i)
        int i = idx & 1023, o = idx >> 10;
        float4 v = *(const float4*)(w + ((size_t)o << 12) + (i << 2));
        bf16_t* base = wt + ((size_t)o << 12) + i;
        base[0]    = (bf16_t)v.x;
        base[1024] = (bf16_t)v.y;
        base[2048] = (bf16_t)v.z;
        base[3072] = (bf16_t)v.w;
    } else {                                // casts, 4 elems/thread
        const float* s; bf16_t* d;
        if (bx < 16384)      { s = video; d = Vb;     bx -= 12288; }
        else if (bx < 17664) { s = words; d = Wordsb; bx -= 16384; }
        else if (bx < 18688) { s = c1dw;  d = C1b;    bx -= 17664; }
        else                 { s = fcw;   d = Fb;     bx -= 18688; }
        int off = (bx * 256 + threadIdx.x) * 4;
        float4 v = *(const float4*)(s + off);
        bf16x4 o4 = { (bf16_t)v.x, (bf16_t)v.y, (bf16_t)v.z, (bf16_t)v.w };
        *(bf16x4*)(d + off) = o4;
    }
}

// ---------------- 64x64 bf16 MFMA NT split-K GEMM (double-buffered) ----------
// XOR-swizzled LDS, global_load_lds width-16 staging. Slice z -> CP + z*cpSlice.
// fcTile: blockIdx.x at which A switches to row aRow0 and B switches to B2.
__global__ __launch_bounds__(256) void mgemm_kernel(
    const bf16_t* __restrict__ A, const bf16_t* __restrict__ B,
    const bf16_t* __restrict__ B2, float* __restrict__ CP,
    int N, int K, int Kchunk, int fcTile, int aRow0, int cpSlice)
{
    __shared__ __align__(16) bf16_t sA[2][4096];
    __shared__ __align__(16) bf16_t sB[2][4096];
    const int tid  = threadIdx.x;
    const int lane = tid & 63;
    const int wave = tid >> 6;
    const int bx = blockIdx.x;
    const int m0C = bx * 64;
    int m0A = m0C;
    const bf16_t* Buse = B;
    if (bx == fcTile) { m0A = aRow0; Buse = B2; }
    const int n0 = blockIdx.y * 64;
    const int k0 = blockIdx.z * Kchunk;

    const int sr = tid >> 3;
    const int pc = tid & 7;
    const int lc = pc ^ (sr & 7);
    const bf16_t* Ag = A + (size_t)(m0A + sr) * K + lc * 8;
    const bf16_t* Bg = Buse + (size_t)(n0 + sr) * K + lc * 8;
    const size_t rowskip = (size_t)32 * K;

    const int wr = (wave >> 1) * 32;
    const int wc = (wave & 1) * 32;
    const int fm = lane & 15;
    const int cb = lane >> 4;

    int offA[2][2], offB[2][2];
    #pragma unroll
    for (int h = 0; h < 2; h++) {
        offA[h][0] = swz(wr +      fm, cb + h * 4);
        offA[h][1] = swz(wr + 16 + fm, cb + h * 4);
        offB[h][0] = swz(wc +      fm, cb + h * 4);
        offB[h][1] = swz(wc + 16 + fm, cb + h * 4);
    }

    f32x4 acc[2][2];
    #pragma unroll
    for (int a = 0; a < 2; a++)
        #pragma unroll
        for (int b = 0; b < 2; b++) acc[a][b] = (f32x4){0.f, 0.f, 0.f, 0.f};

    const int nIt = Kchunk >> 6;
    {
        const bf16_t* a = Ag + k0; const bf16_t* b = Bg + k0;
        gload_lds16(a,           &sA[0][tid * 8]);
        gload_lds16(a + rowskip, &sA[0][2048 + tid * 8]);
        gload_lds16(b,           &sB[0][tid * 8]);
        gload_lds16(b + rowskip, &sB[0][2048 + tid * 8]);
    }
    for (int it = 0; it < nIt; ++it) {
        const int buf = it & 1;
        __syncthreads();
        if (it + 1 < nIt) {
            const bf16_t* a = Ag + k0 + (it + 1) * 64;
            const bf16_t* b = Bg + k0 + (it + 1) * 64;
            bf16_t* dA = &sA[buf ^ 1][0];
            bf16_t* dB = &sB[buf ^ 1][0];
            gload_lds16(a,           dA + tid * 8);
            gload_lds16(a + rowskip, dA + 2048 + tid * 8);
            gload_lds16(b,           dB + tid * 8);
            gload_lds16(b + rowskip, dB + 2048 + tid * 8);
        }
        #pragma unroll
        for (int h = 0; h < 2; h++) {
            bf16x8 a0 = *(const bf16x8*)&sA[buf][offA[h][0]];
            bf16x8 a1 = *(const bf16x8*)&sA[buf][offA[h][1]];
            bf16x8 b0 = *(const bf16x8*)&sB[buf][offB[h][0]];
            bf16x8 b1 = *(const bf16x8*)&sB[buf][offB[h][1]];
            acc[0][0] = __builtin_amdgcn_mfma_f32_16x16x32_bf16(a0, b0, acc[0][0], 0, 0, 0);
            acc[0][1] = __builtin_amdgcn_mfma_f32_16x16x32_bf16(a0, b1, acc[0][1], 0, 0, 0);
            acc[1][0] = __builtin_amdgcn_mfma_f32_16x16x32_bf16(a1, b0, acc[1][0], 0, 0, 0);
            acc[1][1] = __builtin_amdgcn_mfma_f32_16x16x32_bf16(a1, b1, acc[1][1], 0, 0, 0);
        }
    }

    // C/D layout: col = lane&15, row = (lane>>4)*4 + reg   [verified m89/m91]
    float* Cz = CP + (size_t)blockIdx.z * cpSlice;
    #pragma unroll
    for (int im = 0; im < 2; im++)
        #pragma unroll
        for (int rr = 0; rr < 4; rr++) {
            int gm = m0C + wr + im * 16 + cb * 4 + rr;
            #pragma unroll
            for (int in_ = 0; in_ < 2; in_++) {
                int cg = n0 + wc + in_ * 16 + fm;
                Cz[(size_t)gm * N + cg] = acc[im][in_][rr];
            }
        }
}

// ------- split-K reduce + bias + relu -> bf16 -------------------------------
__global__ void epilogueB_kernel(const float* __restrict__ CP_, int nz,
    const float* __restrict__ bias, bf16_t* __restrict__ D, int MN, int N, int relu)
{
    int idx = blockIdx.x * 256 + threadIdx.x;
    if (idx >= MN) return;
    int n = idx % N;
    float s = 0.f;
    for (int z = 0; z < nz; z++) s += CP_[(size_t)z * MN + idx];
    if (bias) s += bias[n];
    if (relu) s = fmaxf(s, 0.f);
    D[idx] = (bf16_t)s;
}

// ------- conv1d+fc combined epilogue (4 split-K slices) -----------------------
__global__ void epilogueCF_kernel(const float* __restrict__ CP_,
    const float* __restrict__ bias1, const float* __restrict__ biasf,
    bf16_t* __restrict__ VCb, float* __restrict__ GV)
{
    int idx = blockIdx.x * 256 + threadIdx.x;       // < 1441792
    int row = idx >> 10, n = idx & 1023;
    float s = CP_[idx] + CP_[idx + 1441792] + CP_[idx + 2 * 1441792] + CP_[idx + 3 * 1441792];
    if (row < 1344) VCb[(size_t)remap1(row) * 1024 + n] = (bf16_t)(s + bias1[n]);
    else            GV[(size_t)(row - 1344) * 1024 + n] = s + biasf[n];
}

// ------- fused rownorm (blocks <1344) + gram (blocks >=1344) ------------------
__global__ void normgram_kernel(const bf16_t* __restrict__ VCb, float* __restrict__ VN,
                                const bf16_t* __restrict__ Wb, float* __restrict__ G)
{
    int bx = blockIdx.x;
    if (bx < 1344) {
        const bf16_t* x = VCb + ((size_t)bx << 10);
        float s = 0.f;
        for (int d = threadIdx.x; d < 1024; d += 256) { float v = (float)x[d]; s += v * v; }
        #pragma unroll
        for (int o = 32; o; o >>= 1) s += __shfl_xor(s, o, 64);
        __shared__ float red[4];
        if ((threadIdx.x & 63) == 0) red[threadIdx.x >> 6] = s;
        __syncthreads();
        if (threadIdx.x == 0) VN[bx] = sqrtf(red[0] + red[1] + red[2] + red[3]);
    } else {
        int g = bx - 1344;                 // 0..6399
        int i = g / 100, piece = g % 100;
        int wave = threadIdx.x >> 6, lane = threadIdx.x & 63;
        int pair = piece * 4 + wave;       // 0..399
        int w = pair / 20, w2 = pair % 20;
        const bf16_t* a = Wb + (((size_t)i * 20 + w)  << 10) + lane * 16;
        const bf16_t* b = Wb + (((size_t)i * 20 + w2) << 10) + lane * 16;
        bf16x8 a0 = *(const bf16x8*)a, a1 = *(const bf16x8*)(a + 8);
        bf16x8 b0 = *(const bf16x8*)b, b1 = *(const bf16x8*)(b + 8);
        float s = 0.f;
        #pragma unroll
        for (int e = 0; e < 8; e++)
            s += (float)a0[e] * (float)b0[e] + (float)a1[e] * (float)b1[e];
        #pragma unroll
        for (int o = 32; o; o >>= 1) s += __shfl_xor(s, o, 64);
        if (lane == 0) G[(size_t)i * 400 + pair] = s;
    }
}

// ------- fused sim + scores-mean + positive_map: one block per i --------------
// Per item jt=(j,t): softmax over 20 masked logits (2 split-K slices of CPat),
// quadratic form vs LDS Gram -> sim. Sims staged in LDS; then 64 lanes reduce
// 21 t's each -> SC[i][j]; i==j rows go straight to out[1..1344].
__global__ __launch_bounds__(256) void simscores_kernel(
    const float* __restrict__ CPat, const float* __restrict__ G_,
    const float* __restrict__ VN_, const int* __restrict__ wmask,
    float* __restrict__ SC_, float* __restrict__ out)
{
    __shared__ float Gs[400];
    __shared__ float msk[20];
    __shared__ float simbuf[1344];
    const int i = blockIdx.x;
    for (int q = threadIdx.x; q < 400; q += 256) Gs[q] = G_[(size_t)i * 400 + q];
    if (threadIdx.x < 20) msk[threadIdx.x] = (wmask[i * 20 + threadIdx.x] != 0) ? 1.f : 0.f;
    __syncthreads();

    for (int base = 0; base < 1344; base += 256) {
        int jt = base + threadIdx.x;
        if (jt < 1344) {
            float s[20], p[20];
            float mx = -1e30f;
            #pragma unroll
            for (int w = 0; w < 20; w++) {
                size_t q = (size_t)(i * 20 + w) * 1344 + jt;
                s[w] = CPat[q] + CPat[q + 1720320];
                if (msk[w] != 0.f) mx = fmaxf(mx, s[w]);
            }
            float denom = 0.f, num = 0.f;
            #pragma unroll
            for (int w = 0; w < 20; w++) {
                p[w] = (msk[w] != 0.f) ? __expf(s[w] - mx) : 0.f;
                denom += p[w];
                num   += p[w] * s[w];
            }
            float quad = 0.f;
            #pragma unroll
            for (int w = 0; w < 20; w++) {
                float c = 0.f;
                #pragma unroll
                for (int w2 = 0; w2 < 20; w2++) c += Gs[w * 20 + w2] * p[w2];
                quad += p[w] * c;
            }
            float dot = num / denom;
            float vsn = sqrtf(fmaxf(quad, 0.f)) / denom;
            float sim = dot / (fmaxf(VN_[jt], 1e-8f) * fmaxf(vsn, 1e-8f));
            simbuf[jt] = sim;
            if (jt / 21 == i) out[1 + i * 21 + (jt % 21)] = sim;   // positive_map
        }
    }
    __syncthreads();
    if (threadIdx.x < 64) {
        int j = threadIdx.x;
        float s = 0.f;
        #pragma unroll
        for (int t = 0; t < 21; t++) s += simbuf[j * 21 + t];
        SC_[i * 64 + j] = s * (1.0f / 21.0f);
    }
}

// ------- global-branch cosine scores (l2norm folded in algebraically) ---------
// GS[i,j] = dot(sent_i, GV_j) / (max(||sent_i||,eps) * max(||GV_j||,eps))
__global__ void gscore_kernel(const float* __restrict__ sent, const float* __restrict__ GV,
                              float* __restrict__ GS_) {
    int item = blockIdx.x * 4 + (threadIdx.x >> 6);  // 4096
    int i = item >> 6, j = item & 63;
    int lane = threadIdx.x & 63;
    const float* a = sent + (size_t)i * 1024;
    const float* b = GV + (size_t)j * 1024;
    float sab = 0.f, saa = 0.f, sbb = 0.f;
    #pragma unroll
    for (int q = 0; q < 16; q++) {
        int d = lane + 64 * q;
        float av = a[d], bv = b[d];
        sab += av * bv; saa += av * av; sbb += bv * bv;
    }
    #pragma unroll
    for (int o = 32; o; o >>= 1) {
        sab += __shfl_xor(sab, o, 64);
        saa += __shfl_xor(saa, o, 64);
        sbb += __shfl_xor(sbb, o, 64);
    }
    if (lane == 0)
        GS_[item] = sab / (fmaxf(sqrtf(saa), 1e-8f) * fmaxf(sqrtf(sbb), 1e-8f));
}

// ---------------- margin ranking loss -----------------------------------------
__global__ void loss_kernel(const float* __restrict__ SC_, const float* __restrict__ GS_,
                            float* __restrict__ out) {
    __shared__ float d1[64], d2[64], red[4];
    int tid = threadIdx.x;
    if (tid < 64) { d1[tid] = SC_[tid * 65]; d2[tid] = GS_[tid * 65]; }
    __syncthreads();
    float acc = 0.f;
    for (int idx = tid; idx < 4096; idx += 256) {
        int i = idx >> 6, j = idx & 63;
        if (i != j) {
            float s = SC_[idx];
            acc += fmaxf(0.2f + s - d1[i], 0.f) + fmaxf(0.2f + s - d1[j], 0.f);
            float g = GS_[idx];
            acc += fmaxf(0.2f + g - d2[i], 0.f) + fmaxf(0.2f + g - d2[j], 0.f);
        }
    }
    #pragma unroll
    for (int o = 32; o; o >>= 1) acc += __shfl_xor(acc, o, 64);
    if ((tid & 63) == 0) red[tid >> 6] = acc;
    __syncthreads();
    if (tid == 0) out[0] = (red[0] + red[1] + red[2] + red[3]) * (1.0f / 64.0f);
}

// ------------------------------------------------------------------------------
extern "C" void kernel_launch(void* const* d_in, const int* in_sizes, int n_in,
                              void* d_out, int out_size, void* d_ws, size_t ws_size,
                              hipStream_t stream)
{
    const float* video     = (const float*)d_in[0];
    const float* words     = (const float*)d_in[1];
    const int*   w_masks   = (const int*)  d_in[2];
    const float* sentences = (const float*)d_in[3];
    const float* conv0_w   = (const float*)d_in[4];
    const float* conv0_b   = (const float*)d_in[5];
    const float* conv1_w   = (const float*)d_in[6];
    const float* conv1_b   = (const float*)d_in[7];
    const float* conv2_w   = (const float*)d_in[8];
    const float* conv2_b   = (const float*)d_in[9];
    const float* conv1d_w  = (const float*)d_in[10];
    const float* conv1d_b  = (const float*)d_in[11];
    const float* fc_w      = (const float*)d_in[12];
    const float* fc_b      = (const float*)d_in[13];
    float* out = (float*)d_out;
    float* ws = (float*)d_ws;

    // ---- flat workspace (float units) = R6 layout, no aliasing ---------------
    bf16_t* WT0    = (bf16_t*)(ws + 0);            // 1024x4096 bf16
    bf16_t* WT1    = (bf16_t*)(ws + 2097152);
    bf16_t* WT2    = (bf16_t*)(ws + 4194304);
    bf16_t* Vb     = (bf16_t*)(ws + 6291456);      // 4,194,304 bf16
    bf16_t* Wordsb = (bf16_t*)(ws + 8388608);      // 1,310,720 bf16
    bf16_t* C1b    = (bf16_t*)(ws + 9043968);      // 1,048,576 bf16
    bf16_t* Fb     = (bf16_t*)(ws + 9568256);      // 1,048,576 bf16
    bf16_t* Astack = (bf16_t*)(ws + 10092544);     // 1344x1024 bf16
    bf16_t* VCb    = (bf16_t*)(ws + 10780672);     // 1344x1024 bf16
    float*  CP0    = ws + 11468800;                // 4 x 1,048,576 f
    float*  CP1    = ws + 15663104;                // 16 x 262,144 f
    float*  CP2    = ws + 19857408;                // 32 x 65,536 f
    float*  CPcf   = ws + 21954560;                // 4 x 1,441,792 f
    float*  CPat   = ws + 27721728;                // 2 x 1,720,320 f
    float*  VN     = ws + 31162368;                // 1,344
    float*  GR     = ws + 31163712;                // 25,600
    float*  SC     = ws + 31189312;                // 4,096
    float*  GV     = ws + 31193408;                // 65,536
    float*  GS     = ws + 31258944;                // 4,096 (ends 31,263,040)

    bf16_t* A2b = Astack + 1048576;   // rows 1024..1279
    bf16_t* A3b = Astack + 1310720;   // rows 1280..1343

    dim3 blk(256);

    // 1. prep: all transposes + casts
    prep_kernel<<<19712, blk, 0, stream>>>(
        conv0_w, conv1_w, conv2_w, WT0, WT1, WT2,
        video, Vb, words, Wordsb, conv1d_w, C1b, fc_w, Fb);

    // 2-3. conv0: M=1024 N=1024 K=4096, split-K x4 -> 1024 blocks (4/CU)
    mgemm_kernel<<<dim3(16,16,4), blk, 0, stream>>>(
        Vb, WT0, nullptr, CP0, 1024, 4096, 1024, -1, 0, 1048576);
    epilogueB_kernel<<<4096, blk, 0, stream>>>(CP0, 4, conv0_b, Astack, 1048576, 1024, 1);

    // 4-5. conv1: M=256 K=4096, split-K x16 -> 1024 blocks
    mgemm_kernel<<<dim3(4,16,16), blk, 0, stream>>>(
        Astack, WT1, nullptr, CP1, 1024, 4096, 256, -1, 0, 262144);
    epilogueB_kernel<<<1024, blk, 0, stream>>>(CP1, 16, conv1_b, A2b, 262144, 1024, 1);

    // 6-7. conv2: M=64 K=4096, split-K x32 -> 512 blocks
    mgemm_kernel<<<dim3(1,16,32), blk, 0, stream>>>(
        A2b, WT2, nullptr, CP2, 1024, 4096, 128, -1, 0, 65536);
    epilogueB_kernel<<<256, blk, 0, stream>>>(CP2, 32, conv2_b, A3b, 65536, 1024, 1);

    // 8-9. conv1d (M=1344) + fc (M=64) in ONE launch; split-K x4 -> 1408 blocks
    mgemm_kernel<<<dim3(22,16,4), blk, 0, stream>>>(
        Astack, C1b, Fb, CPcf, 1024, 1024, 256, 21, 1280, 1441792);
    epilogueCF_kernel<<<5632, blk, 0, stream>>>(CPcf, conv1d_b, fc_b, VCb, GV);

    // 10. attention logits TRANSPOSED, split-K x2 -> 840 blocks:
    //     CPat[z][(i,w)][(j,t)] = partial Wordsb . VCb^T ; simscores sums slices.
    mgemm_kernel<<<dim3(20,21,2), blk, 0, stream>>>(
        Wordsb, VCb, nullptr, CPat, 1344, 1024, 512, -1, 0, 1720320);

    // 11-14. tail
    normgram_kernel<<<7744, blk, 0, stream>>>(VCb, VN, Wordsb, GR);
    simscores_kernel<<<64, blk, 0, stream>>>(CPat, GR, VN, w_masks, SC, out);
    gscore_kernel<<<1024, blk, 0, stream>>>(sentences, GV, GS);
    loss_kernel<<<1, blk, 0, stream>>>(SC, GS, out);
}

// Round 9
// 238.243 us; speedup vs baseline: 1.0649x; 1.0649x over previous
//
#include <hip/hip_runtime.h>
#include <cmath>
#include <cstdint>

// B=64, T=64, W=20, D=1024, K=4, STRIDE=4 ; conv lengths 64->16->4->1 ; T_total=21

typedef __bf16 bf16_t;
typedef bf16_t bf16x8 __attribute__((ext_vector_type(8)));
typedef bf16_t bf16x4 __attribute__((ext_vector_type(4)));
typedef float  f32x4  __attribute__((ext_vector_type(4)));

__device__ __forceinline__ void gload_lds16(const void* g, void* l) {
    __builtin_amdgcn_global_load_lds(
        (const __attribute__((address_space(1))) void*)g,
        (__attribute__((address_space(3))) void*)l, 16, 0, 0);
}

// swizzled LDS offset (bf16 units): physical chunk = c ^ (row&7). [R3: conflicts->0]
__device__ __forceinline__ int swz(int r, int c) { return (r * 8 + (c ^ (r & 7))) * 8; }

// conv1d stack row remap -> VC row j*21 + t
__device__ __forceinline__ int remap1(int gm) {
    if (gm < 1024) return (gm >> 4) * 21 + (gm & 15);
    if (gm < 1280) { int g = gm - 1024; return (g >> 2) * 21 + 16 + (g & 3); }
    return (gm - 1280) * 21 + 20;
}

// ---------------- prep: 3 weight transposes + 4 casts in ONE kernel -----------
__global__ void prep_kernel(
    const float* __restrict__ c0w, const float* __restrict__ c1w,
    const float* __restrict__ c2w,
    bf16_t* __restrict__ WT0, bf16_t* __restrict__ WT1, bf16_t* __restrict__ WT2,
    const float* __restrict__ video, bf16_t* __restrict__ Vb,
    const float* __restrict__ words, bf16_t* __restrict__ Wordsb,
    const float* __restrict__ c1dw, bf16_t* __restrict__ C1b,
    const float* __restrict__ fcw, bf16_t* __restrict__ Fb)
{
    int bx = blockIdx.x;
    if (bx < 12288) {                       // transpose: wt[o][k*1024+i] = w[o][i*4+k]
        const float* w; bf16_t* wt;
        if (bx < 4096)      { w = c0w; wt = WT0; }
        else if (bx < 8192) { w = c1w; wt = WT1; bx -= 4096; }
        else                { w = c2w; wt = WT2; bx -= 8192; }
        int idx = bx * 256 + threadIdx.x;   // (o,i)
        int i = idx & 1023, o = idx >> 10;
        float4 v = *(const float4*)(w + ((size_t)o << 12) + (i << 2));
        bf16_t* base = wt + ((size_t)o << 12) + i;
        base[0]    = (bf16_t)v.x;
        base[1024] = (bf16_t)v.y;
        base[2048] = (bf16_t)v.z;
        base[3072] = (bf16_t)v.w;
    } else {                                // casts, 4 elems/thread
        const float* s; bf16_t* d;
        if (bx < 16384)      { s = video; d = Vb;     bx -= 12288; }
        else if (bx < 17664) { s = words; d = Wordsb; bx -= 16384; }
        else if (bx < 18688) { s = c1dw;  d = C1b;    bx -= 17664; }
        else                 { s = fcw;   d = Fb;     bx -= 18688; }
        int off = (bx * 256 + threadIdx.x) * 4;
        float4 v = *(const float4*)(s + off);
        bf16x4 o4 = { (bf16_t)v.x, (bf16_t)v.y, (bf16_t)v.z, (bf16_t)v.w };
        *(bf16x4*)(d + off) = o4;
    }
}

// ---------------- 64x64 bf16 MFMA NT split-K GEMM (double-buffered) ----------
__global__ __launch_bounds__(256) void mgemm_kernel(
    const bf16_t* __restrict__ A, const bf16_t* __restrict__ B,
    const bf16_t* __restrict__ B2, float* __restrict__ CP,
    int N, int K, int Kchunk, int fcTile, int aRow0, int cpSlice)
{
    __shared__ __align__(16) bf16_t sA[2][4096];
    __shared__ __align__(16) bf16_t sB[2][4096];
    const int tid  = threadIdx.x;
    const int lane = tid & 63;
    const int wave = tid >> 6;
    const int bx = blockIdx.x;
    const int m0C = bx * 64;
    int m0A = m0C;
    const bf16_t* Buse = B;
    if (bx == fcTile) { m0A = aRow0; Buse = B2; }
    const int n0 = blockIdx.y * 64;
    const int k0 = blockIdx.z * Kchunk;

    const int sr = tid >> 3;
    const int pc = tid & 7;
    const int lc = pc ^ (sr & 7);
    const bf16_t* Ag = A + (size_t)(m0A + sr) * K + lc * 8;
    const bf16_t* Bg = Buse + (size_t)(n0 + sr) * K + lc * 8;
    const size_t rowskip = (size_t)32 * K;

    const int wr = (wave >> 1) * 32;
    const int wc = (wave & 1) * 32;
    const int fm = lane & 15;
    const int cb = lane >> 4;

    int offA[2][2], offB[2][2];
    #pragma unroll
    for (int h = 0; h < 2; h++) {
        offA[h][0] = swz(wr +      fm, cb + h * 4);
        offA[h][1] = swz(wr + 16 + fm, cb + h * 4);
        offB[h][0] = swz(wc +      fm, cb + h * 4);
        offB[h][1] = swz(wc + 16 + fm, cb + h * 4);
    }

    f32x4 acc[2][2];
    #pragma unroll
    for (int a = 0; a < 2; a++)
        #pragma unroll
        for (int b = 0; b < 2; b++) acc[a][b] = (f32x4){0.f, 0.f, 0.f, 0.f};

    const int nIt = Kchunk >> 6;
    {
        const bf16_t* a = Ag + k0; const bf16_t* b = Bg + k0;
        gload_lds16(a,           &sA[0][tid * 8]);
        gload_lds16(a + rowskip, &sA[0][2048 + tid * 8]);
        gload_lds16(b,           &sB[0][tid * 8]);
        gload_lds16(b + rowskip, &sB[0][2048 + tid * 8]);
    }
    for (int it = 0; it < nIt; ++it) {
        const int buf = it & 1;
        __syncthreads();
        if (it + 1 < nIt) {
            const bf16_t* a = Ag + k0 + (it + 1) * 64;
            const bf16_t* b = Bg + k0 + (it + 1) * 64;
            bf16_t* dA = &sA[buf ^ 1][0];
            bf16_t* dB = &sB[buf ^ 1][0];
            gload_lds16(a,           dA + tid * 8);
            gload_lds16(a + rowskip, dA + 2048 + tid * 8);
            gload_lds16(b,           dB + tid * 8);
            gload_lds16(b + rowskip, dB + 2048 + tid * 8);
        }
        #pragma unroll
        for (int h = 0; h < 2; h++) {
            bf16x8 a0 = *(const bf16x8*)&sA[buf][offA[h][0]];
            bf16x8 a1 = *(const bf16x8*)&sA[buf][offA[h][1]];
            bf16x8 b0 = *(const bf16x8*)&sB[buf][offB[h][0]];
            bf16x8 b1 = *(const bf16x8*)&sB[buf][offB[h][1]];
            acc[0][0] = __builtin_amdgcn_mfma_f32_16x16x32_bf16(a0, b0, acc[0][0], 0, 0, 0);
            acc[0][1] = __builtin_amdgcn_mfma_f32_16x16x32_bf16(a0, b1, acc[0][1], 0, 0, 0);
            acc[1][0] = __builtin_amdgcn_mfma_f32_16x16x32_bf16(a1, b0, acc[1][0], 0, 0, 0);
            acc[1][1] = __builtin_amdgcn_mfma_f32_16x16x32_bf16(a1, b1, acc[1][1], 0, 0, 0);
        }
    }

    // C/D layout: col = lane&15, row = (lane>>4)*4 + reg   [verified m89/m91]
    float* Cz = CP + (size_t)blockIdx.z * cpSlice;
    #pragma unroll
    for (int im = 0; im < 2; im++)
        #pragma unroll
        for (int rr = 0; rr < 4; rr++) {
            int gm = m0C + wr + im * 16 + cb * 4 + rr;
            #pragma unroll
            for (int in_ = 0; in_ < 2; in_++) {
                int cg = n0 + wc + in_ * 16 + fm;
                Cz[(size_t)gm * N + cg] = acc[im][in_][rr];
            }
        }
}

// ------- attn GEMM (blocks <840) + rownorm (840..2183) + gram (>=2184) --------
// GEMM: CPat[z][(i,w)][(j,t)] partial = Wordsb . VCb^T, M=1280 N=1344 K=1024,
// split-K x2 (Kchunk 512). Independent of normgram -> one dispatch, co-issue.
__global__ __launch_bounds__(256) void attn_ng_kernel(
    const bf16_t* __restrict__ A, const bf16_t* __restrict__ B,
    float* __restrict__ CP,
    const bf16_t* __restrict__ VCb, float* __restrict__ VN,
    const bf16_t* __restrict__ Wb, float* __restrict__ G)
{
    __shared__ __align__(16) bf16_t sA[2][4096];
    __shared__ __align__(16) bf16_t sB[2][4096];
    __shared__ float red[4];
    const int bxg = blockIdx.x;
    const int tid = threadIdx.x;

    if (bxg < 840) {
        // ---- GEMM path: z = bxg/420, x = tile%20 (M), y = tile/20 (N) ----
        const int z = bxg / 420;
        const int rem = bxg - z * 420;
        const int xt = rem % 20, yt = rem / 20;
        const int lane = tid & 63;
        const int wave = tid >> 6;
        const int m0 = xt * 64, n0 = yt * 64;
        const int k0 = z * 512;
        const int N = 1344, K = 1024;

        const int sr = tid >> 3;
        const int pc = tid & 7;
        const int lc = pc ^ (sr & 7);
        const bf16_t* Ag = A + (size_t)(m0 + sr) * K + lc * 8;
        const bf16_t* Bg = B + (size_t)(n0 + sr) * K + lc * 8;
        const size_t rowskip = (size_t)32 * K;

        const int wr = (wave >> 1) * 32;
        const int wc = (wave & 1) * 32;
        const int fm = lane & 15;
        const int cb = lane >> 4;

        int offA[2][2], offB[2][2];
        #pragma unroll
        for (int h = 0; h < 2; h++) {
            offA[h][0] = swz(wr +      fm, cb + h * 4);
            offA[h][1] = swz(wr + 16 + fm, cb + h * 4);
            offB[h][0] = swz(wc +      fm, cb + h * 4);
            offB[h][1] = swz(wc + 16 + fm, cb + h * 4);
        }

        f32x4 acc[2][2];
        #pragma unroll
        for (int a = 0; a < 2; a++)
            #pragma unroll
            for (int b = 0; b < 2; b++) acc[a][b] = (f32x4){0.f, 0.f, 0.f, 0.f};

        {
            const bf16_t* a = Ag + k0; const bf16_t* b = Bg + k0;
            gload_lds16(a,           &sA[0][tid * 8]);
            gload_lds16(a + rowskip, &sA[0][2048 + tid * 8]);
            gload_lds16(b,           &sB[0][tid * 8]);
            gload_lds16(b + rowskip, &sB[0][2048 + tid * 8]);
        }
        for (int it = 0; it < 8; ++it) {
            const int buf = it & 1;
            __syncthreads();
            if (it + 1 < 8) {
                const bf16_t* a = Ag + k0 + (it + 1) * 64;
                const bf16_t* b = Bg + k0 + (it + 1) * 64;
                bf16_t* dA = &sA[buf ^ 1][0];
                bf16_t* dB = &sB[buf ^ 1][0];
                gload_lds16(a,           dA + tid * 8);
                gload_lds16(a + rowskip, dA + 2048 + tid * 8);
                gload_lds16(b,           dB + tid * 8);
                gload_lds16(b + rowskip, dB + 2048 + tid * 8);
            }
            #pragma unroll
            for (int h = 0; h < 2; h++) {
                bf16x8 a0 = *(const bf16x8*)&sA[buf][offA[h][0]];
                bf16x8 a1 = *(const bf16x8*)&sA[buf][offA[h][1]];
                bf16x8 b0 = *(const bf16x8*)&sB[buf][offB[h][0]];
                bf16x8 b1 = *(const bf16x8*)&sB[buf][offB[h][1]];
                acc[0][0] = __builtin_amdgcn_mfma_f32_16x16x32_bf16(a0, b0, acc[0][0], 0, 0, 0);
                acc[0][1] = __builtin_amdgcn_mfma_f32_16x16x32_bf16(a0, b1, acc[0][1], 0, 0, 0);
                acc[1][0] = __builtin_amdgcn_mfma_f32_16x16x32_bf16(a1, b0, acc[1][0], 0, 0, 0);
                acc[1][1] = __builtin_amdgcn_mfma_f32_16x16x32_bf16(a1, b1, acc[1][1], 0, 0, 0);
            }
        }

        float* Cz = CP + (size_t)z * 1720320;
        #pragma unroll
        for (int im = 0; im < 2; im++)
            #pragma unroll
            for (int rr = 0; rr < 4; rr++) {
                int gm = m0 + wr + im * 16 + cb * 4 + rr;
                #pragma unroll
                for (int in_ = 0; in_ < 2; in_++) {
                    int cg = n0 + wc + in_ * 16 + fm;
                    Cz[(size_t)gm * N + cg] = acc[im][in_][rr];
                }
            }
    } else if (bxg < 2184) {
        // ---- rownorm path: ||VCb row|| ----
        int r = bxg - 840;
        const bf16_t* x = VCb + ((size_t)r << 10);
        float s = 0.f;
        for (int d = tid; d < 1024; d += 256) { float v = (float)x[d]; s += v * v; }
        #pragma unroll
        for (int o = 32; o; o >>= 1) s += __shfl_xor(s, o, 64);
        if ((tid & 63) == 0) red[tid >> 6] = s;
        __syncthreads();
        if (tid == 0) VN[r] = sqrtf(red[0] + red[1] + red[2] + red[3]);
    } else {
        // ---- gram path: one wave per (w,w') pair ----
        int g = bxg - 2184;                // 0..6399
        int i = g / 100, piece = g % 100;
        int wave = tid >> 6, lane = tid & 63;
        int pair = piece * 4 + wave;       // 0..399
        int w = pair / 20, w2 = pair % 20;
        const bf16_t* a = Wb + (((size_t)i * 20 + w)  << 10) + lane * 16;
        const bf16_t* b = Wb + (((size_t)i * 20 + w2) << 10) + lane * 16;
        bf16x8 a0 = *(const bf16x8*)a, a1 = *(const bf16x8*)(a + 8);
        bf16x8 b0 = *(const bf16x8*)b, b1 = *(const bf16x8*)(b + 8);
        float s = 0.f;
        #pragma unroll
        for (int e = 0; e < 8; e++)
            s += (float)a0[e] * (float)b0[e] + (float)a1[e] * (float)b1[e];
        #pragma unroll
        for (int o = 32; o; o >>= 1) s += __shfl_xor(s, o, 64);
        if (lane == 0) G[(size_t)i * 400 + pair] = s;
    }
}

// ------- split-K reduce + bias + relu -> bf16 -------------------------------
__global__ void epilogueB_kernel(const float* __restrict__ CP_, int nz,
    const float* __restrict__ bias, bf16_t* __restrict__ D, int MN, int N, int relu)
{
    int idx = blockIdx.x * 256 + threadIdx.x;
    if (idx >= MN) return;
    int n = idx % N;
    float s = 0.f;
    for (int z = 0; z < nz; z++) s += CP_[(size_t)z * MN + idx];
    if (bias) s += bias[n];
    if (relu) s = fmaxf(s, 0.f);
    D[idx] = (bf16_t)s;
}

// ------- conv1d+fc combined epilogue (4 split-K slices) -----------------------
__global__ void epilogueCF_kernel(const float* __restrict__ CP_,
    const float* __restrict__ bias1, const float* __restrict__ biasf,
    bf16_t* __restrict__ VCb, float* __restrict__ GV)
{
    int idx = blockIdx.x * 256 + threadIdx.x;       // < 1441792
    int row = idx >> 10, n = idx & 1023;
    float s = CP_[idx] + CP_[idx + 1441792] + CP_[idx + 2 * 1441792] + CP_[idx + 3 * 1441792];
    if (row < 1344) VCb[(size_t)remap1(row) * 1024 + n] = (bf16_t)(s + bias1[n]);
    else            GV[(size_t)(row - 1344) * 1024 + n] = s + biasf[n];
}

// ---------------- sim: one THREAD per (i, jt); reads 2 split-K slices ---------
__global__ __launch_bounds__(256) void sim_kernel(
    const float* __restrict__ CPat, const float* __restrict__ G_,
    const float* __restrict__ VN_, const int* __restrict__ wmask,
    float* __restrict__ SA_)
{
    __shared__ float Gs[400];
    __shared__ float msk[20];
    const int i  = blockIdx.x;
    const int jt = blockIdx.y * 256 + threadIdx.x;   // 0..1535 (1344 used)
    for (int q = threadIdx.x; q < 400; q += 256) Gs[q] = G_[(size_t)i * 400 + q];
    if (threadIdx.x < 20) msk[threadIdx.x] = (wmask[i * 20 + threadIdx.x] != 0) ? 1.f : 0.f;
    __syncthreads();
    if (jt >= 1344) return;

    float s[20], p[20];
    float mx = -1e30f;
    #pragma unroll
    for (int w = 0; w < 20; w++) {
        size_t q = (size_t)(i * 20 + w) * 1344 + jt;
        s[w] = CPat[q] + CPat[q + 1720320];
        if (msk[w] != 0.f) mx = fmaxf(mx, s[w]);
    }
    float denom = 0.f, num = 0.f;
    #pragma unroll
    for (int w = 0; w < 20; w++) {
        p[w] = (msk[w] != 0.f) ? __expf(s[w] - mx) : 0.f;
        denom += p[w];
        num   += p[w] * s[w];
    }
    float quad = 0.f;
    #pragma unroll
    for (int w = 0; w < 20; w++) {
        float c = 0.f;
        #pragma unroll
        for (int w2 = 0; w2 < 20; w2++) c += Gs[w * 20 + w2] * p[w2];
        quad += p[w] * c;
    }
    float dot = num / denom;
    float vsn = sqrtf(fmaxf(quad, 0.f)) / denom;
    float sim = dot / (fmaxf(VN_[jt], 1e-8f) * fmaxf(vsn, 1e-8f));
    SA_[(size_t)i * 1344 + jt] = sim;
}

// ------- scores+positive_map (blocks <16) + gscore w/ algebraic norms (>=16) --
__global__ void sg_kernel(const float* __restrict__ SA_, float* __restrict__ SC_,
                          float* __restrict__ out,
                          const float* __restrict__ sent, const float* __restrict__ GV,
                          float* __restrict__ GS_)
{
    int bx = blockIdx.x;
    if (bx < 16) {
        int idx = bx * 256 + threadIdx.x;  // 4096 = i*64+j
        int i = idx >> 6, j = idx & 63;
        const float* row = SA_ + (size_t)idx * 21;
        float s = 0.f;
        #pragma unroll
        for (int t = 0; t < 21; t++) s += row[t];
        SC_[idx] = s * (1.0f / 21.0f);
        if (i == j) {
            #pragma unroll
            for (int t = 0; t < 21; t++) out[1 + i * 21 + t] = row[t];
        }
    } else {
        int item = (bx - 16) * 4 + (threadIdx.x >> 6);  // 4096
        int i = item >> 6, j = item & 63;
        int lane = threadIdx.x & 63;
        const float* a = sent + (size_t)i * 1024;
        const float* b = GV + (size_t)j * 1024;
        float sab = 0.f, saa = 0.f, sbb = 0.f;
        #pragma unroll
        for (int q = 0; q < 16; q++) {
            int d = lane + 64 * q;
            float av = a[d], bv = b[d];
            sab += av * bv; saa += av * av; sbb += bv * bv;
        }
        #pragma unroll
        for (int o = 32; o; o >>= 1) {
            sab += __shfl_xor(sab, o, 64);
            saa += __shfl_xor(saa, o, 64);
            sbb += __shfl_xor(sbb, o, 64);
        }
        if (lane == 0)
            GS_[item] = sab / (fmaxf(sqrtf(saa), 1e-8f) * fmaxf(sqrtf(sbb), 1e-8f));
    }
}

// ---------------- margin ranking loss -----------------------------------------
__global__ void loss_kernel(const float* __restrict__ SC_, const float* __restrict__ GS_,
                            float* __restrict__ out) {
    __shared__ float d1[64], d2[64], red[4];
    int tid = threadIdx.x;
    if (tid < 64) { d1[tid] = SC_[tid * 65]; d2[tid] = GS_[tid * 65]; }
    __syncthreads();
    float acc = 0.f;
    for (int idx = tid; idx < 4096; idx += 256) {
        int i = idx >> 6, j = idx & 63;
        if (i != j) {
            float s = SC_[idx];
            acc += fmaxf(0.2f + s - d1[i], 0.f) + fmaxf(0.2f + s - d1[j], 0.f);
            float g = GS_[idx];
            acc += fmaxf(0.2f + g - d2[i], 0.f) + fmaxf(0.2f + g - d2[j], 0.f);
        }
    }
    #pragma unroll
    for (int o = 32; o; o >>= 1) acc += __shfl_xor(acc, o, 64);
    if ((tid & 63) == 0) red[tid >> 6] = acc;
    __syncthreads();
    if (tid == 0) out[0] = (red[0] + red[1] + red[2] + red[3]) * (1.0f / 64.0f);
}

// ------------------------------------------------------------------------------
extern "C" void kernel_launch(void* const* d_in, const int* in_sizes, int n_in,
                              void* d_out, int out_size, void* d_ws, size_t ws_size,
                              hipStream_t stream)
{
    const float* video     = (const float*)d_in[0];
    const float* words     = (const float*)d_in[1];
    const int*   w_masks   = (const int*)  d_in[2];
    const float* sentences = (const float*)d_in[3];
    const float* conv0_w   = (const float*)d_in[4];
    const float* conv0_b   = (const float*)d_in[5];
    const float* conv1_w   = (const float*)d_in[6];
    const float* conv1_b   = (const float*)d_in[7];
    const float* conv2_w   = (const float*)d_in[8];
    const float* conv2_b   = (const float*)d_in[9];
    const float* conv1d_w  = (const float*)d_in[10];
    const float* conv1d_b  = (const float*)d_in[11];
    const float* fc_w      = (const float*)d_in[12];
    const float* fc_b      = (const float*)d_in[13];
    float* out = (float*)d_out;
    float* ws = (float*)d_ws;

    // ---- flat workspace (float units) = R6 layout ----------------------------
    bf16_t* WT0    = (bf16_t*)(ws + 0);            // 1024x4096 bf16
    bf16_t* WT1    = (bf16_t*)(ws + 2097152);
    bf16_t* WT2    = (bf16_t*)(ws + 4194304);
    bf16_t* Vb     = (bf16_t*)(ws + 6291456);      // 4,194,304 bf16
    bf16_t* Wordsb = (bf16_t*)(ws + 8388608);      // 1,310,720 bf16
    bf16_t* C1b    = (bf16_t*)(ws + 9043968);      // 1,048,576 bf16
    bf16_t* Fb     = (bf16_t*)(ws + 9568256);      // 1,048,576 bf16
    bf16_t* Astack = (bf16_t*)(ws + 10092544);     // 1344x1024 bf16
    bf16_t* VCb    = (bf16_t*)(ws + 10780672);     // 1344x1024 bf16
    float*  CP0    = ws + 11468800;                // 4 x 1,048,576 f
    float*  CP1    = ws + 15663104;                // 16 x 262,144 f
    float*  CP2    = ws + 19857408;                // 32 x 65,536 f
    float*  CPcf   = ws + 21954560;                // 4 x 1,441,792 f
    float*  CPat   = ws + 27721728;                // 2 x 1,720,320 f
    float*  VN     = ws + 31162368;                // 1,344
    float*  GR     = ws + 31163712;                // 25,600
    float*  SA     = ws + 31189312;                // 86,016
    float*  SC     = ws + 31275328;                // 4,096
    float*  GV     = ws + 31279424;                // 65,536
    float*  GS     = ws + 31344960;                // 4,096 (ends 31,349,056)

    bf16_t* A2b = Astack + 1048576;   // rows 1024..1279
    bf16_t* A3b = Astack + 1310720;   // rows 1280..1343

    dim3 blk(256);

    // 1. prep: all transposes + casts
    prep_kernel<<<19712, blk, 0, stream>>>(
        conv0_w, conv1_w, conv2_w, WT0, WT1, WT2,
        video, Vb, words, Wordsb, conv1d_w, C1b, fc_w, Fb);

    // 2-3. conv0: M=1024 N=1024 K=4096, split-K x4 -> 1024 blocks (4/CU)
    mgemm_kernel<<<dim3(16,16,4), blk, 0, stream>>>(
        Vb, WT0, nullptr, CP0, 1024, 4096, 1024, -1, 0, 1048576);
    epilogueB_kernel<<<4096, blk, 0, stream>>>(CP0, 4, conv0_b, Astack, 1048576, 1024, 1);

    // 4-5. conv1: M=256 K=4096, split-K x16 -> 1024 blocks
    mgemm_kernel<<<dim3(4,16,16), blk, 0, stream>>>(
        Astack, WT1, nullptr, CP1, 1024, 4096, 256, -1, 0, 262144);
    epilogueB_kernel<<<1024, blk, 0, stream>>>(CP1, 16, conv1_b, A2b, 262144, 1024, 1);

    // 6-7. conv2: M=64 K=4096, split-K x32 -> 512 blocks
    mgemm_kernel<<<dim3(1,16,32), blk, 0, stream>>>(
        A2b, WT2, nullptr, CP2, 1024, 4096, 128, -1, 0, 65536);
    epilogueB_kernel<<<256, blk, 0, stream>>>(CP2, 32, conv2_b, A3b, 65536, 1024, 1);

    // 8-9. conv1d (M=1344) + fc (M=64) in ONE launch; split-K x4 -> 1408 blocks
    mgemm_kernel<<<dim3(22,16,4), blk, 0, stream>>>(
        Astack, C1b, Fb, CPcf, 1024, 1024, 256, 21, 1280, 1441792);
    epilogueCF_kernel<<<5632, blk, 0, stream>>>(CPcf, conv1d_b, fc_b, VCb, GV);

    // 10. attn GEMM (840 blocks) + rownorm (1344) + gram (6400) in ONE dispatch
    attn_ng_kernel<<<8584, blk, 0, stream>>>(
        Wordsb, VCb, CPat, VCb, VN, Wordsb, GR);

    // 11-13. tail
    sim_kernel<<<dim3(64,6), blk, 0, stream>>>(CPat, GR, VN, w_masks, SA);
    sg_kernel<<<1040, blk, 0, stream>>>(SA, SC, out, sentences, GV, GS);
    loss_kernel<<<1, blk, 0, stream>>>(SC, GS, out);
}